// Round 14
// baseline (153.082 us; speedup 1.0000x reference)
//
#include <hip/hip_runtime.h>
#include <math.h>

#define N_NODES 50000
#define NPAD    50048      // 391 * 128 (mega uses 64-row tiles: 782 blocks)
#define F_IN    128
#define HID     256
#define NCLS    40
#define CAP     96         // per-node edge bucket capacity; P(deg>=96) ~ 1e-48
#define NB_FILL 2048       // 8 partitions x 256 slices

typedef __attribute__((ext_vector_type(8))) short bf16x8;
typedef __attribute__((ext_vector_type(4))) float f32x4;

__device__ inline ushort f2bf(float f) {
    uint u = __builtin_bit_cast(uint, f);
    u += 0x7FFF + ((u >> 16) & 1);          // round-to-nearest-even
    return (ushort)(u >> 16);
}
__device__ inline float bf2f(uint h16) {
    uint u = h16 << 16;
    return __builtin_bit_cast(float, u);
}

// ---------------- prep: zero fillpos + cast x->bf16 + pack weights ----------------

__global__ void prep_kernel(const float* __restrict__ x, ushort* __restrict__ xb,
                            const float* __restrict__ W1l, const float* __restrict__ W1r,
                            const float* __restrict__ W2l, const float* __restrict__ W2r,
                            ushort* __restrict__ Wb1, ushort* __restrict__ Wb2,
                            int* __restrict__ fillpos) {
    int b = blockIdx.x, t = threadIdx.x;
    if (b < 196) {
        int i = b * 256 + t;
        if (i < N_NODES) fillpos[i] = 0;
    } else if (b < 6446) {
        int i = (b - 196) * 256 + t;     // < 1,600,000 exactly
        float4 v = *reinterpret_cast<const float4*>(x + (size_t)i * 4);
        ushort4 o;
        o.x = f2bf(v.x); o.y = f2bf(v.y); o.z = f2bf(v.z); o.w = f2bf(v.w);
        *reinterpret_cast<ushort4*>(xb + (size_t)i * 4) = o;
    } else {
        int i = (b - 6446) * 256 + t;    // < 86016 exactly
        if (i < 65536) {
            int n = i >> 8, k = i & 255;
            float v = (k < 128) ? W1l[n * 128 + k] : W1r[n * 128 + (k - 128)];
            Wb1[i] = f2bf(v);
        } else {
            int j = i - 65536;           // < 20480
            int n = j >> 8, k = j & 255;
            float v = (n < 40) ? W2l[n * 256 + k] : W2r[(n - 40) * 256 + k];
            Wb2[j] = f2bf(v);
        }
    }
}

// ---------------- XCD-partitioned bucket fill ----------
// col2 is LAYER-MAJOR ushort: col2[p*N + n] = p-th in-neighbor of node n.

__global__ void fill_kernel(const int* __restrict__ src, const int* __restrict__ dst,
                            int* __restrict__ fillpos, ushort* __restrict__ col2, int E) {
    const int pid = blockIdx.x & 7;
    const int slice = blockIdx.x >> 3;                 // 0..255
    for (int i = slice * 256 + threadIdx.x; i < E; i += (NB_FILL >> 3) * 256) {
        int d = dst[i];
        if (((uint)(d * 164) >> 20) == (uint)pid) {
            int p = atomicAdd(&fillpos[d], 1);
            if (p < CAP) col2[(size_t)p * N_NODES + d] = (ushort)src[i];
        }
    }
}

#define ACC8(A, V) \
    A[0] += bf2f(V.x & 0xffffu); A[1] += bf2f(V.x >> 16); \
    A[2] += bf2f(V.y & 0xffffu); A[3] += bf2f(V.y >> 16); \
    A[4] += bf2f(V.z & 0xffffu); A[5] += bf2f(V.z >> 16); \
    A[6] += bf2f(V.w & 0xffffu); A[7] += bf2f(V.w >> 16);

// ---------------- MEGA: agg128 + GEMM1 + GEMM2 fused ----------------
// Block owns 64 rows. LDS 48KB: [0,32K) B1-quarter staging (later h-stage
// overlay, 4 waves x 8KB); [32K,48K) A_agg (64 rows x 128 bf16, swizzled).
// Phase A: 16-lane slots gather-mean the block's rows (4-deep MLP, fires deg>=4).
// GEMM1: 4 quarters of 64 B1-cols; A-frags hoisted to regs (agg from LDS, x from
// global). h never touches global: epilogue -> per-wave LDS, GEMM2 reads it.

__global__ __launch_bounds__(256, 3) void mega_kernel(const ushort* __restrict__ xb,
                                                      const int* __restrict__ fillpos,
                                                      const ushort* __restrict__ col2,
                                                      const ushort* __restrict__ Wb1,
                                                      const float* __restrict__ b1,
                                                      const ushort* __restrict__ Wb2,
                                                      const float* __restrict__ b2,
                                                      ushort* __restrict__ hWb,
                                                      ushort* __restrict__ selfb) {
    __shared__ __align__(16) char S[49152];
    const int t = threadIdx.x, w = t >> 6, l = t & 63;
    const int bm = blockIdx.x * 64;
    const int lr = l & 15, lg = l >> 4;

    // ---- Phase A: mean-agg of this block's 64 rows into A_agg ----
    {
        const int s = t >> 4, fl = t & 15;      // slot, feature-lane
#pragma unroll
        for (int chunk = 0; chunk < 4; ++chunk) {
            int lrow = s + chunk * 16;          // 0..63
            int n = bm + lrow;
            int deg = (n < N_NODES) ? min(fillpos[n], CAP) : 0;
            float a0[8] = {}, a1[8] = {}, a2[8] = {}, a3[8] = {};
            int j = 0;
            for (; j + 3 < deg; j += 4) {
                int c0 = col2[(size_t)j * N_NODES + n];
                int c1 = col2[(size_t)(j + 1) * N_NODES + n];
                int c2 = col2[(size_t)(j + 2) * N_NODES + n];
                int c3 = col2[(size_t)(j + 3) * N_NODES + n];
                uint4 v0 = *reinterpret_cast<const uint4*>(xb + (size_t)c0 * F_IN + fl * 8);
                uint4 v1 = *reinterpret_cast<const uint4*>(xb + (size_t)c1 * F_IN + fl * 8);
                uint4 v2 = *reinterpret_cast<const uint4*>(xb + (size_t)c2 * F_IN + fl * 8);
                uint4 v3 = *reinterpret_cast<const uint4*>(xb + (size_t)c3 * F_IN + fl * 8);
                ACC8(a0, v0) ACC8(a1, v1) ACC8(a2, v2) ACC8(a3, v3)
            }
            for (; j < deg; ++j) {
                int c = col2[(size_t)j * N_NODES + n];
                uint4 v = *reinterpret_cast<const uint4*>(xb + (size_t)c * F_IN + fl * 8);
                ACC8(a0, v)
            }
            float inv = 1.0f / (float)max(deg, 1);
            uint4 o;
            o.x = (uint)f2bf((a0[0] + a1[0] + a2[0] + a3[0]) * inv) |
                  ((uint)f2bf((a0[1] + a1[1] + a2[1] + a3[1]) * inv) << 16);
            o.y = (uint)f2bf((a0[2] + a1[2] + a2[2] + a3[2]) * inv) |
                  ((uint)f2bf((a0[3] + a1[3] + a2[3] + a3[3]) * inv) << 16);
            o.z = (uint)f2bf((a0[4] + a1[4] + a2[4] + a3[4]) * inv) |
                  ((uint)f2bf((a0[5] + a1[5] + a2[5] + a3[5]) * inv) << 16);
            o.w = (uint)f2bf((a0[6] + a1[6] + a2[6] + a3[6]) * inv) |
                  ((uint)f2bf((a0[7] + a1[7] + a2[7] + a3[7]) * inv) << 16);
            *reinterpret_cast<uint4*>(S + 32768 + ((lrow * 256 + fl * 16) ^ ((lrow & 7) << 4))) = o;
        }
    }
    __syncthreads();

    // ---- GEMM1: hoist A-frags, then 4 quarters of B1 ----
    bf16x8 aa[4], ax[4];
    {
        int lrow = w * 16 + lr;
#pragma unroll
        for (int kk = 0; kk < 4; ++kk) {
            aa[kk] = *reinterpret_cast<const bf16x8*>(
                S + 32768 + ((lrow * 256 + kk * 64 + lg * 16) ^ ((lrow & 7) << 4)));
            ax[kk] = *reinterpret_cast<const bf16x8*>(
                xb + (size_t)(bm + lrow) * F_IN + kk * 32 + lg * 8);
        }
    }
    f32x4 acc[16] = {};
#pragma unroll
    for (int q = 0; q < 4; ++q) {
        for (int i = t; i < 64 * 32; i += 256) {        // 32KB quarter staging
            int nn = i >> 5, k8 = (i & 31) * 8;
            uint4 v = *reinterpret_cast<const uint4*>(Wb1 + (size_t)(q * 64 + nn) * 256 + k8);
            *reinterpret_cast<uint4*>(S + ((nn * 512 + k8 * 2) ^ ((nn & 7) << 4))) = v;
        }
        __syncthreads();
#pragma unroll
        for (int kt = 0; kt < 8; ++kt) {
            bf16x8 af = (kt < 4) ? aa[kt & 3] : ax[kt & 3];
            int kbyte = kt * 64 + lg * 16;
#pragma unroll
            for (int jl = 0; jl < 4; ++jl) {
                int lc = jl * 16 + lr;
                bf16x8 bf = *reinterpret_cast<const bf16x8*>(
                    S + ((lc * 512 + kbyte) ^ ((lc & 7) << 4)));
                acc[q * 4 + jl] = __builtin_amdgcn_mfma_f32_16x16x32_bf16(af, bf, acc[q * 4 + jl], 0, 0, 0);
            }
        }
        __syncthreads();
    }

    // ---- h epilogue -> per-wave h-stage (overlays [0,32K)) ----
#pragma unroll
    for (int jj = 0; jj < 16; ++jj) {
        int c = jj * 16 + lr;
        float bias = b1[c];
#pragma unroll
        for (int r = 0; r < 4; ++r) {
            float v = fmaxf(acc[jj][r] + bias, 0.f);
            int rrow = lg * 4 + r;              // 0..15 local
            *reinterpret_cast<ushort*>(
                S + w * 8192 + ((rrow * 512 + c * 2) ^ ((rrow & 7) << 4))) = f2bf(v);
        }
    }
    __syncthreads();

    // ---- GEMM2: A from own h-stage, B = Wb2 from global ----
    f32x4 acc2[5] = {};
#pragma unroll
    for (int kt = 0; kt < 8; ++kt) {
        int kbyte = kt * 64 + lg * 16;
        bf16x8 af = *reinterpret_cast<const bf16x8*>(
            S + w * 8192 + ((lr * 512 + kbyte) ^ ((lr & 7) << 4)));
#pragma unroll
        for (int j5 = 0; j5 < 5; ++j5) {
            int nl = j5 * 16 + lr;
            bf16x8 bf = *reinterpret_cast<const bf16x8*>(Wb2 + (size_t)nl * 256 + kt * 32 + lg * 8);
            acc2[j5] = __builtin_amdgcn_mfma_f32_16x16x32_bf16(af, bf, acc2[j5], 0, 0, 0);
        }
    }
#pragma unroll
    for (int j5 = 0; j5 < 5; ++j5) {
        int cfull = j5 * 16 + lr;
#pragma unroll
        for (int r = 0; r < 4; ++r) {
            int row = bm + w * 16 + lg * 4 + r;
            float v = acc2[j5][r];
            if (cfull < 40) {
                hWb[(size_t)row * 64 + cfull] = f2bf(v);          // 128B-aligned rows
            } else {
                int c = cfull - 40;
                selfb[(size_t)row * 40 + c] = f2bf(v + b2[c]);
            }
        }
    }
}

// ---------------- fused: out = log_softmax(self + mean_j hW_j) ----------------

__global__ __launch_bounds__(256) void agg40_lsm_kernel(const ushort* __restrict__ hWb,
                                                        const ushort* __restrict__ selfb,
                                                        const int* __restrict__ fillpos,
                                                        const ushort* __restrict__ col2,
                                                        float* __restrict__ out) {
    int wid = threadIdx.x >> 6, l = threadIdx.x & 63;
    int n = blockIdx.x * 4 + wid;
    if (n >= N_NODES) return;
    int g = l >> 3, lr = l & 7;
    bool ld = lr < 5;
    bool act = (g == 0) && ld;
    int deg = fillpos[n];
    if (deg > CAP) deg = CAP;
    uint4 sv = {};
    if (act) sv = *reinterpret_cast<const uint4*>(selfb + (size_t)n * 40 + lr * 8);
    float a[8] = {}, b[8] = {};
    int j = g;
    if (ld) {
        for (; j + 8 < deg; j += 16) {
            int c0 = col2[(size_t)j * N_NODES + n];
            int c1 = col2[(size_t)(j + 8) * N_NODES + n];
            uint4 v0 = *reinterpret_cast<const uint4*>(hWb + (size_t)c0 * 64 + lr * 8);
            uint4 v1 = *reinterpret_cast<const uint4*>(hWb + (size_t)c1 * 64 + lr * 8);
            ACC8(a, v0) ACC8(b, v1)
        }
        if (j < deg) {
            int c = col2[(size_t)j * N_NODES + n];
            uint4 v = *reinterpret_cast<const uint4*>(hWb + (size_t)c * 64 + lr * 8);
            ACC8(a, v)
        }
    }
#pragma unroll
    for (int i = 0; i < 8; ++i) {
        a[i] += b[i];
        a[i] += __shfl_xor(a[i], 8);
        a[i] += __shfl_xor(a[i], 16);
        a[i] += __shfl_xor(a[i], 32);
    }
    float inv = 1.0f / (float)max(deg, 1);
    float v[8];
    if (act) {
        v[0] = bf2f(sv.x & 0xffffu) + a[0] * inv; v[1] = bf2f(sv.x >> 16) + a[1] * inv;
        v[2] = bf2f(sv.y & 0xffffu) + a[2] * inv; v[3] = bf2f(sv.y >> 16) + a[3] * inv;
        v[4] = bf2f(sv.z & 0xffffu) + a[4] * inv; v[5] = bf2f(sv.z >> 16) + a[5] * inv;
        v[6] = bf2f(sv.w & 0xffffu) + a[6] * inv; v[7] = bf2f(sv.w >> 16) + a[7] * inv;
    } else {
#pragma unroll
        for (int i = 0; i < 8; ++i) v[i] = -INFINITY;
    }
    float m = v[0];
#pragma unroll
    for (int i = 1; i < 8; ++i) m = fmaxf(m, v[i]);
    m = fmaxf(m, __shfl_xor(m, 1));
    m = fmaxf(m, __shfl_xor(m, 2));
    m = fmaxf(m, __shfl_xor(m, 4));
    float ex = 0.f;
    if (act) {
#pragma unroll
        for (int i = 0; i < 8; ++i) ex += expf(v[i] - m);
    }
    ex += __shfl_xor(ex, 1);
    ex += __shfl_xor(ex, 2);
    ex += __shfl_xor(ex, 4);
    float ls = logf(ex);
    if (act) {
        float* ob = out + (size_t)n * NCLS + lr * 8;
        float4 o0, o1;
        o0.x = v[0] - m - ls; o0.y = v[1] - m - ls; o0.z = v[2] - m - ls; o0.w = v[3] - m - ls;
        o1.x = v[4] - m - ls; o1.y = v[5] - m - ls; o1.z = v[6] - m - ls; o1.w = v[7] - m - ls;
        *reinterpret_cast<float4*>(ob) = o0;
        *reinterpret_cast<float4*>(ob + 4) = o1;
    }
}

// ---------------- launch ----------------

static inline size_t align256(size_t x) { return (x + 255) & ~(size_t)255; }

extern "C" void kernel_launch(void* const* d_in, const int* in_sizes, int n_in,
                              void* d_out, int out_size, void* d_ws, size_t ws_size,
                              hipStream_t stream) {
    const float* x    = (const float*)d_in[0];
    const int*   ei   = (const int*)d_in[1];
    const float* W1l  = (const float*)d_in[2];
    const float* b1   = (const float*)d_in[3];
    const float* W1r  = (const float*)d_in[4];
    const float* W2l  = (const float*)d_in[5];
    const float* b2   = (const float*)d_in[6];
    const float* W2r  = (const float*)d_in[7];
    float* out = (float*)d_out;

    const int N = N_NODES;
    const int E = in_sizes[1] / 2;
    const int* srcArr = ei;
    const int* dstArr = ei + E;

    char* ws = (char*)d_ws;
    size_t off = 0;
    auto alloc = [&](size_t bytes) { size_t o = off; off = align256(off + bytes); return o; };
    int*    fillpos  = (int*)(ws + alloc((size_t)N * 4));
    ushort* col2     = (ushort*)(ws + alloc((size_t)CAP * N * 2));   // layer-major
    ushort* xb       = (ushort*)(ws + alloc((size_t)NPAD * F_IN * 2));
    ushort* hWb      = (ushort*)(ws + alloc((size_t)NPAD * 64 * 2));
    ushort* selfb    = (ushort*)(ws + alloc((size_t)NPAD * 40 * 2));
    ushort* Wb1      = (ushort*)(ws + alloc((size_t)256 * 256 * 2));
    ushort* Wb2      = (ushort*)(ws + alloc((size_t)80 * 256 * 2));
    (void)ws_size; (void)n_in; (void)out_size;

    // 1. prep: zero fillpos + cast + pack (streaming only)
    prep_kernel<<<6782, 256, 0, stream>>>(x, xb, W1l, W1r, W2l, W2r, Wb1, Wb2, fillpos);
    // 2. XCD-partitioned fill
    fill_kernel<<<NB_FILL, 256, 0, stream>>>(srcArr, dstArr, fillpos, col2, E);
    // 3. mega: agg128 + gemm1 + gemm2 fused (64-row tiles)
    mega_kernel<<<NPAD / 64, 256, 0, stream>>>(xb, fillpos, col2, Wb1, b1, Wb2, b2, hWb, selfb);
    // 4. layer-2 aggregation + self + log_softmax
    agg40_lsm_kernel<<<(N + 3) / 4, 256, 0, stream>>>(hWb, selfb, fillpos, col2, out);
}

// Round 15
// 130.056 us; speedup vs baseline: 1.1770x; 1.1770x over previous
//
#include <hip/hip_runtime.h>
#include <math.h>

#define N_NODES 50000
#define NPAD    50048      // 391 * 128
#define F_IN    128
#define HID     256
#define NCLS    40
#define CAP     96         // per-node edge bucket capacity; P(deg>=96) ~ 1e-48
#define NB_FILL 2048       // 8 partitions x 256 slices

typedef __attribute__((ext_vector_type(8))) short bf16x8;
typedef __attribute__((ext_vector_type(4))) float f32x4;

__device__ inline ushort f2bf(float f) {
    uint u = __builtin_bit_cast(uint, f);
    u += 0x7FFF + ((u >> 16) & 1);          // round-to-nearest-even
    return (ushort)(u >> 16);
}
__device__ inline float bf2f(uint h16) {
    uint u = h16 << 16;
    return __builtin_bit_cast(float, u);
}

// ---------------- prep: zero fillpos + cast x->bf16 & fp8 + pack weights ----------------
// blocks [0,196): fillpos zero; [196,6446): cast_x (1.6M float4 -> bf16 + fp8);
// [6446,6782): weight pack. Streaming only, no scatter.

__global__ void prep_kernel(const float* __restrict__ x, ushort* __restrict__ xb,
                            uchar* __restrict__ xf8,
                            const float* __restrict__ W1l, const float* __restrict__ W1r,
                            const float* __restrict__ W2l, const float* __restrict__ W2r,
                            ushort* __restrict__ Wb1, ushort* __restrict__ Wb2,
                            int* __restrict__ fillpos) {
    int b = blockIdx.x, t = threadIdx.x;
    if (b < 196) {
        int i = b * 256 + t;
        if (i < N_NODES) fillpos[i] = 0;
    } else if (b < 6446) {
        int i = (b - 196) * 256 + t;     // < 1,600,000 exactly
        float4 v = *reinterpret_cast<const float4*>(x + (size_t)i * 4);
        ushort4 o;
        o.x = f2bf(v.x); o.y = f2bf(v.y); o.z = f2bf(v.z); o.w = f2bf(v.w);
        *reinterpret_cast<ushort4*>(xb + (size_t)i * 4) = o;
        uint w8 = __builtin_amdgcn_cvt_pk_fp8_f32(v.x, v.y, 0u, false);
        w8 = __builtin_amdgcn_cvt_pk_fp8_f32(v.z, v.w, w8, true);
        *reinterpret_cast<uint*>(xf8 + (size_t)i * 4) = w8;
    } else {
        int i = (b - 6446) * 256 + t;    // < 86016 exactly
        if (i < 65536) {
            int n = i >> 8, k = i & 255;
            float v = (k < 128) ? W1l[n * 128 + k] : W1r[n * 128 + (k - 128)];
            Wb1[i] = f2bf(v);
        } else {
            int j = i - 65536;           // < 20480
            int n = j >> 8, k = j & 255;
            float v = (n < 40) ? W2l[n * 256 + k] : W2r[(n - 40) * 256 + k];
            Wb2[j] = f2bf(v);
        }
    }
}

// ---------------- XCD-partitioned bucket fill ----------
// col2 is LAYER-MAJOR ushort: col2[p*N + n] = p-th in-neighbor of node n.

__global__ void fill_kernel(const int* __restrict__ src, const int* __restrict__ dst,
                            int* __restrict__ fillpos, ushort* __restrict__ col2, int E) {
    const int pid = blockIdx.x & 7;
    const int slice = blockIdx.x >> 3;                 // 0..255
    for (int i = slice * 256 + threadIdx.x; i < E; i += (NB_FILL >> 3) * 256) {
        int d = dst[i];
        if (((uint)(d * 164) >> 20) == (uint)pid) {
            int p = atomicAdd(&fillpos[d], 1);
            if (p < CAP) col2[(size_t)p * N_NODES + d] = (ushort)src[i];
        }
    }
}

#define ACC8(A, V) \
    A[0] += bf2f(V.x & 0xffffu); A[1] += bf2f(V.x >> 16); \
    A[2] += bf2f(V.y & 0xffffu); A[3] += bf2f(V.y >> 16); \
    A[4] += bf2f(V.z & 0xffffu); A[5] += bf2f(V.z >> 16); \
    A[6] += bf2f(V.w & 0xffffu); A[7] += bf2f(V.w >> 16);

// fp8 gather accumulate: uint2 = 8 fp8 e4m3 values
#define ACC8F8(A, V) \
    A[0] += __builtin_amdgcn_cvt_f32_fp8(V.x, 0); A[1] += __builtin_amdgcn_cvt_f32_fp8(V.x, 1); \
    A[2] += __builtin_amdgcn_cvt_f32_fp8(V.x, 2); A[3] += __builtin_amdgcn_cvt_f32_fp8(V.x, 3); \
    A[4] += __builtin_amdgcn_cvt_f32_fp8(V.y, 0); A[5] += __builtin_amdgcn_cvt_f32_fp8(V.y, 1); \
    A[6] += __builtin_amdgcn_cvt_f32_fp8(V.y, 2); A[7] += __builtin_amdgcn_cvt_f32_fp8(V.y, 3);

// ---------------- mean aggregation layer 1 (fp8 gather: 128B/row, half traffic) ----------
// 4 groups x 16 lanes x 8B; 2x guarded unroll (degree-appropriate: mean 12.8)

__global__ __launch_bounds__(256) void agg128_kernel(const uchar* __restrict__ xf8,
                                                     const int* __restrict__ fillpos,
                                                     const ushort* __restrict__ col2,
                                                     ushort* __restrict__ aggb) {
    int wid = threadIdx.x >> 6, l = threadIdx.x & 63;
    int n = blockIdx.x * 4 + wid;
    if (n >= N_NODES) return;
    int g = l >> 4, lr = l & 15;
    int deg = fillpos[n];
    if (deg > CAP) deg = CAP;
    float a[8] = {}, b[8] = {};
    int j = g;
    for (; j + 4 < deg; j += 8) {
        int c0 = col2[(size_t)j * N_NODES + n];
        int c1 = col2[(size_t)(j + 4) * N_NODES + n];
        uint2 v0 = *reinterpret_cast<const uint2*>(xf8 + (size_t)c0 * F_IN + lr * 8);
        uint2 v1 = *reinterpret_cast<const uint2*>(xf8 + (size_t)c1 * F_IN + lr * 8);
        ACC8F8(a, v0) ACC8F8(b, v1)
    }
    if (j < deg) {
        int c = col2[(size_t)j * N_NODES + n];
        uint2 v = *reinterpret_cast<const uint2*>(xf8 + (size_t)c * F_IN + lr * 8);
        ACC8F8(a, v)
    }
#pragma unroll
    for (int i = 0; i < 8; ++i) {
        a[i] += b[i];
        a[i] += __shfl_xor(a[i], 16);
        a[i] += __shfl_xor(a[i], 32);
    }
    if (g == 0) {
        float inv = 1.0f / (float)max(deg, 1);
        uint4 o;
        o.x = (uint)f2bf(a[0] * inv) | ((uint)f2bf(a[1] * inv) << 16);
        o.y = (uint)f2bf(a[2] * inv) | ((uint)f2bf(a[3] * inv) << 16);
        o.z = (uint)f2bf(a[4] * inv) | ((uint)f2bf(a[5] * inv) << 16);
        o.w = (uint)f2bf(a[6] * inv) | ((uint)f2bf(a[7] * inv) << 16);
        *reinterpret_cast<uint4*>(aggb + (size_t)n * F_IN + lr * 8) = o;
    }
}

// ---------------- fused GEMM1+GEMM2 ----------------
// Phase 1: h = relu([agg|x] @ Wb1.T + b1), Wb1 staged per-128-col half in 64KB LDS.
// Phase 2: h tile -> same LDS (bf16, swizzled; h never touches global).
// Phase 3: hWb[row][0..39] = h @ W2l.T (row padded to 64 for 128B alignment);
//          selfb[row][0..39] = h @ W2r.T + b2.

__global__ __launch_bounds__(256, 2) void gemm12_kernel(const ushort* __restrict__ aggb,
                                                        const ushort* __restrict__ xb,
                                                        const ushort* __restrict__ Wb1,
                                                        const float* __restrict__ b1,
                                                        const ushort* __restrict__ Wb2,
                                                        const float* __restrict__ b2,
                                                        ushort* __restrict__ hWb,
                                                        ushort* __restrict__ selfb) {
    __shared__ __align__(16) char S[128 * 512];   // 64 KiB: B1-half staging, then h tile
    const int t = threadIdx.x, w = t >> 6, l = t & 63;
    const int bm = blockIdx.x * 128;
    const int lr = l & 15, lg = l >> 4;

    f32x4 acc[2][16] = {};
#pragma unroll
    for (int half = 0; half < 2; ++half) {
        for (int i = t; i < 128 * 32; i += 256) {
            int n = i >> 5, k8 = (i & 31) * 8;
            uint4 v = *reinterpret_cast<const uint4*>(Wb1 + (size_t)(half * 128 + n) * 256 + k8);
            *reinterpret_cast<uint4*>(S + ((n * 512 + k8 * 2) ^ ((n & 7) << 4))) = v;
        }
        __syncthreads();
#pragma unroll
        for (int kt = 0; kt < 8; ++kt) {
            const ushort* Ap = (kt < 4) ? aggb : xb;
            int kb = kt * 32 - ((kt < 4) ? 0 : 128) + lg * 8;
            bf16x8 a0 = *reinterpret_cast<const bf16x8*>(Ap + (size_t)(bm + w * 32 + lr) * F_IN + kb);
            bf16x8 a1 = *reinterpret_cast<const bf16x8*>(Ap + (size_t)(bm + w * 32 + 16 + lr) * F_IN + kb);
            int kbyte = kt * 64 + lg * 16;
#pragma unroll
            for (int j = 0; j < 8; ++j) {
                int nl = j * 16 + lr;
                bf16x8 b = *reinterpret_cast<const bf16x8*>(S + ((nl * 512 + kbyte) ^ ((nl & 7) << 4)));
                acc[0][half * 8 + j] = __builtin_amdgcn_mfma_f32_16x16x32_bf16(a0, b, acc[0][half * 8 + j], 0, 0, 0);
                acc[1][half * 8 + j] = __builtin_amdgcn_mfma_f32_16x16x32_bf16(a1, b, acc[1][half * 8 + j], 0, 0, 0);
            }
        }
        __syncthreads();
    }

    // write h tile (128 x 256 bf16) into S, swizzled, row stride 512B
#pragma unroll
    for (int j = 0; j < 16; ++j) {
        int c = j * 16 + lr;
        float bias = b1[c];
#pragma unroll
        for (int m = 0; m < 2; ++m) {
            int rowb = w * 32 + m * 16 + lg * 4;
#pragma unroll
            for (int r = 0; r < 4; ++r) {
                float v = fmaxf(acc[m][j][r] + bias, 0.f);
                int row = rowb + r;
                *reinterpret_cast<ushort*>(S + ((row * 512 + c * 2) ^ ((row & 7) << 4))) = f2bf(v);
            }
        }
    }
    __syncthreads();

    // GEMM2: A from LDS h, B = Wb2 from global (L2)
    f32x4 acc2[2][5] = {};
#pragma unroll
    for (int kt = 0; kt < 8; ++kt) {
        int kbyte = kt * 64 + lg * 16;
        int r0 = w * 32 + lr, r1 = r0 + 16;
        bf16x8 a0 = *reinterpret_cast<const bf16x8*>(S + ((r0 * 512 + kbyte) ^ ((r0 & 7) << 4)));
        bf16x8 a1 = *reinterpret_cast<const bf16x8*>(S + ((r1 * 512 + kbyte) ^ ((r1 & 7) << 4)));
#pragma unroll
        for (int j = 0; j < 5; ++j) {
            int nl = j * 16 + lr;
            bf16x8 b = *reinterpret_cast<const bf16x8*>(Wb2 + (size_t)nl * 256 + kt * 32 + lg * 8);
            acc2[0][j] = __builtin_amdgcn_mfma_f32_16x16x32_bf16(a0, b, acc2[0][j], 0, 0, 0);
            acc2[1][j] = __builtin_amdgcn_mfma_f32_16x16x32_bf16(a1, b, acc2[1][j], 0, 0, 0);
        }
    }
#pragma unroll
    for (int m = 0; m < 2; ++m) {
        int rbase = bm + w * 32 + m * 16 + lg * 4;
#pragma unroll
        for (int j = 0; j < 5; ++j) {
            int cfull = j * 16 + lr;
#pragma unroll
            for (int r = 0; r < 4; ++r) {
                int row = rbase + r;
                float v = acc2[m][j][r];
                if (cfull < 40) {
                    hWb[(size_t)row * 64 + cfull] = f2bf(v);          // 128B-aligned rows
                } else {
                    int c = cfull - 40;
                    selfb[(size_t)row * 40 + c] = f2bf(v + b2[c]);
                }
            }
        }
    }
}

// ---------------- fused: out = log_softmax(self + mean_j hW_j) ----------------
// 8 groups of 8 lanes; lanes lr<5 load 16B each (80B of an aligned 128B row);
// 2x guarded unroll (degree-appropriate)

__global__ __launch_bounds__(256) void agg40_lsm_kernel(const ushort* __restrict__ hWb,
                                                        const ushort* __restrict__ selfb,
                                                        const int* __restrict__ fillpos,
                                                        const ushort* __restrict__ col2,
                                                        float* __restrict__ out) {
    int wid = threadIdx.x >> 6, l = threadIdx.x & 63;
    int n = blockIdx.x * 4 + wid;
    if (n >= N_NODES) return;
    int g = l >> 3, lr = l & 7;
    bool ld = lr < 5;
    bool act = (g == 0) && ld;
    int deg = fillpos[n];
    if (deg > CAP) deg = CAP;
    // self part issued early (hides under gather chain)
    uint4 sv = {};
    if (act) sv = *reinterpret_cast<const uint4*>(selfb + (size_t)n * 40 + lr * 8);
    float a[8] = {}, b[8] = {};
    int j = g;
    if (ld) {
        for (; j + 8 < deg; j += 16) {
            int c0 = col2[(size_t)j * N_NODES + n];
            int c1 = col2[(size_t)(j + 8) * N_NODES + n];
            uint4 v0 = *reinterpret_cast<const uint4*>(hWb + (size_t)c0 * 64 + lr * 8);
            uint4 v1 = *reinterpret_cast<const uint4*>(hWb + (size_t)c1 * 64 + lr * 8);
            ACC8(a, v0) ACC8(b, v1)
        }
        if (j < deg) {
            int c = col2[(size_t)j * N_NODES + n];
            uint4 v = *reinterpret_cast<const uint4*>(hWb + (size_t)c * 64 + lr * 8);
            ACC8(a, v)
        }
    }
#pragma unroll
    for (int i = 0; i < 8; ++i) {
        a[i] += b[i];
        a[i] += __shfl_xor(a[i], 8);
        a[i] += __shfl_xor(a[i], 16);
        a[i] += __shfl_xor(a[i], 32);
    }
    float inv = 1.0f / (float)max(deg, 1);
    float v[8];
    if (act) {
        v[0] = bf2f(sv.x & 0xffffu) + a[0] * inv; v[1] = bf2f(sv.x >> 16) + a[1] * inv;
        v[2] = bf2f(sv.y & 0xffffu) + a[2] * inv; v[3] = bf2f(sv.y >> 16) + a[3] * inv;
        v[4] = bf2f(sv.z & 0xffffu) + a[4] * inv; v[5] = bf2f(sv.z >> 16) + a[5] * inv;
        v[6] = bf2f(sv.w & 0xffffu) + a[6] * inv; v[7] = bf2f(sv.w >> 16) + a[7] * inv;
    } else {
#pragma unroll
        for (int i = 0; i < 8; ++i) v[i] = -INFINITY;
    }
    float m = v[0];
#pragma unroll
    for (int i = 1; i < 8; ++i) m = fmaxf(m, v[i]);
    m = fmaxf(m, __shfl_xor(m, 1));
    m = fmaxf(m, __shfl_xor(m, 2));
    m = fmaxf(m, __shfl_xor(m, 4));
    float ex = 0.f;
    if (act) {
#pragma unroll
        for (int i = 0; i < 8; ++i) ex += expf(v[i] - m);
    }
    ex += __shfl_xor(ex, 1);
    ex += __shfl_xor(ex, 2);
    ex += __shfl_xor(ex, 4);
    float ls = logf(ex);
    if (act) {
        float* ob = out + (size_t)n * NCLS + lr * 8;
        float4 o0, o1;
        o0.x = v[0] - m - ls; o0.y = v[1] - m - ls; o0.z = v[2] - m - ls; o0.w = v[3] - m - ls;
        o1.x = v[4] - m - ls; o1.y = v[5] - m - ls; o1.z = v[6] - m - ls; o1.w = v[7] - m - ls;
        *reinterpret_cast<float4*>(ob) = o0;
        *reinterpret_cast<float4*>(ob + 4) = o1;
    }
}

// ---------------- launch ----------------

static inline size_t align256(size_t x) { return (x + 255) & ~(size_t)255; }

extern "C" void kernel_launch(void* const* d_in, const int* in_sizes, int n_in,
                              void* d_out, int out_size, void* d_ws, size_t ws_size,
                              hipStream_t stream) {
    const float* x    = (const float*)d_in[0];
    const int*   ei   = (const int*)d_in[1];
    const float* W1l  = (const float*)d_in[2];
    const float* b1   = (const float*)d_in[3];
    const float* W1r  = (const float*)d_in[4];
    const float* W2l  = (const float*)d_in[5];
    const float* b2   = (const float*)d_in[6];
    const float* W2r  = (const float*)d_in[7];
    float* out = (float*)d_out;

    const int N = N_NODES;
    const int E = in_sizes[1] / 2;
    const int* srcArr = ei;
    const int* dstArr = ei + E;

    char* ws = (char*)d_ws;
    size_t off = 0;
    auto alloc = [&](size_t bytes) { size_t o = off; off = align256(off + bytes); return o; };
    int*    fillpos  = (int*)(ws + alloc((size_t)N * 4));
    ushort* col2     = (ushort*)(ws + alloc((size_t)CAP * N * 2));   // layer-major
    ushort* xb       = (ushort*)(ws + alloc((size_t)NPAD * F_IN * 2));
    uchar*  xf8      = (uchar*)(ws + alloc((size_t)NPAD * F_IN));
    ushort* aggb     = (ushort*)(ws + alloc((size_t)NPAD * F_IN * 2));
    ushort* hWb      = (ushort*)(ws + alloc((size_t)NPAD * 64 * 2));
    ushort* selfb    = (ushort*)(ws + alloc((size_t)NPAD * 40 * 2));
    ushort* Wb1      = (ushort*)(ws + alloc((size_t)256 * 256 * 2));
    ushort* Wb2      = (ushort*)(ws + alloc((size_t)80 * 256 * 2));
    (void)ws_size; (void)n_in; (void)out_size;

    // 1. prep: zero fillpos + cast (bf16 + fp8) + pack (streaming only)
    prep_kernel<<<6782, 256, 0, stream>>>(x, xb, xf8, W1l, W1r, W2l, W2r, Wb1, Wb2, fillpos);
    // 2. XCD-partitioned fill
    fill_kernel<<<NB_FILL, 256, 0, stream>>>(srcArr, dstArr, fillpos, col2, E);
    // 3. layer-1 mean aggregation (fp8 gather, half traffic)
    agg128_kernel<<<(N + 3) / 4, 256, 0, stream>>>(xf8, fillpos, col2, aggb);
    // 4. fused gemm1+gemm2 (h stays in LDS; aggregated part -> hWb, self part -> selfb)
    gemm12_kernel<<<NPAD / 128, 256, 0, stream>>>(aggb, xb, Wb1, b1, Wb2, b2, hWb, selfb);
    // 5. layer-2 aggregation + self + log_softmax
    agg40_lsm_kernel<<<(N + 3) / 4, 256, 0, stream>>>(hWb, selfb, fillpos, col2, out);
}